// Round 20
// baseline (126.362 us; speedup 1.0000x reference)
//
#include <hip/hip_runtime.h>
#include <math.h>

#define BB 8
#define NN 512
#define FF 128
#define TT 32
#define DD 64
constexpr float EPS = 1e-6f;

typedef _Float16 half8 __attribute__((ext_vector_type(8)));
typedef float f32x4 __attribute__((ext_vector_type(4)));

extern __shared__ char dynsmem[];

__device__ __forceinline__ float fast_tanh(float v) {
    float e = __expf(2.f * v);
    return 1.f - 2.f * __builtin_amdgcn_rcpf(e + 1.f);
}

// ---------------- Stage 0: split W into MFMA-fragment-layout fp16 hi/lo tables ----------------
__global__ __launch_bounds__(256) void wsplit_kernel(const float* __restrict__ W,
                                                     _Float16* __restrict__ whF,
                                                     _Float16* __restrict__ wlF) {
    const int tid = threadIdx.x;
    #pragma unroll
    for (int k = 0; k < 4; ++k) {
        int u   = tid + k * 256;          // 0..1023
        int g   = u & 3;
        int l15 = (u >> 2) & 15;
        int sd  = u >> 6;                 // s*4+dt
        int s   = sd >> 2;
        int dt  = sd & 3;
        const float* src = W + (dt * 16 + l15) * 128 + s * 32 + g * 8;
        half8 hv, lv;
        #pragma unroll
        for (int i = 0; i < 8; ++i) {
            float f = src[i];
            hv[i] = (_Float16)f;
            lv[i] = (_Float16)(f - (float)hv[i]);
        }
        ((half8*)whF)[u] = hv;
        ((half8*)wlF)[u] = lv;
    }
}

// ---------------- Stage 1: z = tanh(x @ W^T + b) via split-fp16 MFMA (unchanged) ----------------
__global__ __launch_bounds__(256) void z8_kernel(const float* __restrict__ x,
                                                 const _Float16* __restrict__ whF,
                                                 const _Float16* __restrict__ wlF,
                                                 const float* __restrict__ bias,
                                                 _Float16* __restrict__ zh,
                                                 _Float16* __restrict__ zl,
                                                 float* __restrict__ sqv,
                                                 float* __restrict__ nvv,
                                                 float* __restrict__ nvi) {
    float* xs = (float*)dynsmem;          // 4 waves x 32 t x 132 f (padded)
    const int tid = threadIdx.x;
    const int b  = blockIdx.x >> 7;
    const int n0 = (blockIdx.x & 127) * 4;

    const float4* x4 = (const float4*)(x + ((size_t)b * NN + n0) * FF * TT);
    #pragma unroll
    for (int it = 0; it < 16; ++it) {
        int idx4 = tid + it * 256;
        float4 v = x4[idx4];
        int e   = idx4 * 4;
        int ns  = e >> 12;
        int rem = e & 4095;
        int f   = rem >> 5;
        int t   = rem & 31;
        float* base = xs + ns * 4224 + t * 132 + f;
        base[0 * 132] = v.x;
        base[1 * 132] = v.y;
        base[2 * 132] = v.z;
        base[3 * 132] = v.w;
    }
    __syncthreads();

    const int w    = tid >> 6;
    const int lane = tid & 63;
    const int l15  = lane & 15;
    const int g    = lane >> 4;
    const int n    = n0 + w;
    float* xs_w = xs + w * 4224;

    half8 wh[16];
    #pragma unroll
    for (int sd = 0; sd < 16; ++sd)
        wh[sd] = ((const half8*)whF)[sd * 64 + l15 * 4 + g];

    float bb[4];
    #pragma unroll
    for (int dt = 0; dt < 4; ++dt) bb[dt] = bias[dt * 16 + l15];

    f32x4 acc[4][2];
    #pragma unroll
    for (int dt = 0; dt < 4; ++dt)
        #pragma unroll
        for (int tt = 0; tt < 2; ++tt) acc[dt][tt] = f32x4{0.f, 0.f, 0.f, 0.f};

    #pragma unroll
    for (int s = 0; s < 4; ++s) {
        half8 ah[2], al[2];
        #pragma unroll
        for (int tt = 0; tt < 2; ++tt) {
            const float* ap = xs_w + (tt * 16 + l15) * 132 + s * 32 + g * 8;
            float4 p0 = *(const float4*)ap;
            float4 p1 = *(const float4*)(ap + 4);
            float fv[8] = {p0.x, p0.y, p0.z, p0.w, p1.x, p1.y, p1.z, p1.w};
            #pragma unroll
            for (int i = 0; i < 8; ++i) {
                ah[tt][i] = (_Float16)fv[i];
                al[tt][i] = (_Float16)(fv[i] - (float)ah[tt][i]);
            }
        }
        #pragma unroll
        for (int dt = 0; dt < 4; ++dt) {
            half8 wl_ = ((const half8*)wlF)[(s * 4 + dt) * 64 + l15 * 4 + g];
            acc[dt][0] = __builtin_amdgcn_mfma_f32_16x16x32_f16(ah[0], wh[s * 4 + dt], acc[dt][0], 0, 0, 0);
            acc[dt][1] = __builtin_amdgcn_mfma_f32_16x16x32_f16(ah[1], wh[s * 4 + dt], acc[dt][1], 0, 0, 0);
            acc[dt][0] = __builtin_amdgcn_mfma_f32_16x16x32_f16(al[0], wh[s * 4 + dt], acc[dt][0], 0, 0, 0);
            acc[dt][1] = __builtin_amdgcn_mfma_f32_16x16x32_f16(al[1], wh[s * 4 + dt], acc[dt][1], 0, 0, 0);
            acc[dt][0] = __builtin_amdgcn_mfma_f32_16x16x32_f16(ah[0], wl_, acc[dt][0], 0, 0, 0);
            acc[dt][1] = __builtin_amdgcn_mfma_f32_16x16x32_f16(ah[1], wl_, acc[dt][1], 0, 0, 0);
        }
    }

    float* zsw = xs_w;
    #pragma unroll
    for (int dt = 0; dt < 4; ++dt)
        #pragma unroll
        for (int tt = 0; tt < 2; ++tt)
            #pragma unroll
            for (int ri = 0; ri < 4; ++ri) {
                float zf = fast_tanh(acc[dt][tt][ri] + bb[dt]);
                zsw[(tt * 16 + g * 4 + ri) * 68 + dt * 16 + l15] = zf;
            }

    const int tr = lane >> 1;
    const int ob = (lane & 1) * 4;
    const size_t rowidx = ((size_t)b * TT + tr) * NN + n;
    _Float16* zhp = zh + rowidx * DD;
    _Float16* zlp = zl + rowidx * DD;
    float sqp = 0.f;
    #pragma unroll
    for (int j = 0; j < 4; ++j) {
        int oct = ob + j;
        const float* qp = zsw + tr * 68 + oct * 8;
        float4 q0 = *(const float4*)qp;
        float4 q1 = *(const float4*)(qp + 4);
        float fv[8] = {q0.x, q0.y, q0.z, q0.w, q1.x, q1.y, q1.z, q1.w};
        half8 hv, lv;
        #pragma unroll
        for (int i = 0; i < 8; ++i) {
            sqp += fv[i] * fv[i];
            hv[i] = (_Float16)fv[i];
            lv[i] = (_Float16)(fv[i] - (float)hv[i]);
        }
        const int so = (oct ^ (n & 7)) * 8;
        *(half8*)(zhp + so) = hv;
        *(half8*)(zlp + so) = lv;
    }
    float sqf = sqp + __shfl_xor(sqp, 1);
    if (!(lane & 1)) {
        float nv = sqrtf(sqf) + EPS;
        sqv[rowidx] = sqf;
        nvv[rowidx] = nv;
        nvi[rowidx] = __builtin_amdgcn_rcpf(nv);
    }
}

// ---------------- Stage 2: b-split wave-teams, 16-row blocks, 24 waves/CU ----------------
// grid: 1024 blocks (t = bid&31, rowgroup16 = bid>>5), 512 threads = 8 waves.
// team tm = w>>2 (A: b 0..3, B: b 4..7); cg = w&3 (128 cols each). Per-wave shape == att15.
// LDS: os[16][516] | rs[2 tm][2 p][4 cg][16]
#define RSOFS   33024
#define LDSSZ_ATT 34048

__global__ __launch_bounds__(512, 2) void att16_kernel(const _Float16* __restrict__ zh,
                                                       const _Float16* __restrict__ zl,
                                                       const float* __restrict__ sqv,
                                                       const float* __restrict__ nvv,
                                                       const float* __restrict__ nvi,
                                                       float* __restrict__ out) {
    char* lds = dynsmem;
    float* os   = (float*)lds;
    float* rs_s = (float*)(lds + RSOFS);   // [tm][p][cg][16]
    const int tid  = threadIdx.x;
    const int w    = tid >> 6;
    const int lane = tid & 63;
    const int l15  = lane & 15;
    const int g    = lane >> 4;
    const int tm   = w >> 2;
    const int cg   = w & 3;
    const int t    = blockIdx.x & 31;
    const int rg   = blockIdx.x >> 5;
    const int n0   = rg * 16;

    float acc[8][4];
    #pragma unroll
    for (int ct = 0; ct < 8; ++ct)
        #pragma unroll
        for (int ri = 0; ri < 4; ++ri) acc[ct][ri] = 0.f;

    float att_f[8][4];

    // loop-invariant swizzled octet offsets (elements)
    const int kq = l15 & 7;
    const int e0 = (g ^ kq) * 8;
    const int e1 = ((4 + g) ^ kq) * 8;
    const int arow = n0 + l15;

    #pragma unroll 1
    for (int step = 0; step < 4; ++step) {
        const int b  = tm * 4 + step;
        const int pb = step & 1;
        const size_t nbase = ((size_t)b * TT + t) * NN;
        const size_t slab  = nbase * DD;

        // A fragments from global (swizzled layout)
        half8 ah[2], al[2];
        {
            const size_t ro = slab + (size_t)arow * DD;
            ah[0] = *(const half8*)(zh + ro + e0);
            ah[1] = *(const half8*)(zh + ro + e1);
            al[0] = *(const half8*)(zl + ro + e0);
            al[1] = *(const half8*)(zl + ro + e1);
        }
        // row norms from global (L2-hot); nri loaded, not computed
        float nrE[4], sq_r[4], nri[4];
        #pragma unroll
        for (int ri = 0; ri < 4; ++ri) {
            const int rrow = n0 + g * 4 + ri;
            nrE[ri]  = nvv[nbase + rrow] + EPS;
            sq_r[ri] = sqv[nbase + rrow];
            nri[ri]  = nvi[nbase + rrow];
        }

        float rs[4] = {0.f, 0.f, 0.f, 0.f};

        // depth-3 software pipeline over the 8 col-tiles (ct stride = 16 cols = 1024 elems)
        const _Float16* cb  = zh + slab + (size_t)(cg * 128 + l15) * DD;
        const float*    nvp = nvv + nbase + cg * 128 + l15;
        const float*    sqp = sqv + nbase + cg * 128 + l15;
        const float*    nip = nvi + nbase + cg * 128 + l15;
        half8 pb0[3], pb1[3];
        float pnm[3], psq[3], pni[3];
        #pragma unroll
        for (int p = 0; p < 3; ++p) {
            pb0[p] = *(const half8*)(cb + p * 1024 + e0);
            pb1[p] = *(const half8*)(cb + p * 1024 + e1);
            pnm[p] = nvp[p * 16];
            psq[p] = sqp[p * 16];
            pni[p] = nip[p * 16];
        }
        #pragma unroll
        for (int ct = 0; ct < 8; ++ct) {
            const int slot = ct % 3;       // compile-time under full unroll
            half8 bh0c = pb0[slot], bh1c = pb1[slot];
            float nmc = pnm[slot], sqmc = psq[slot], nmi = pni[slot];
            if (ct + 3 < 8) {
                pb0[slot] = *(const half8*)(cb + (ct + 3) * 1024 + e0);
                pb1[slot] = *(const half8*)(cb + (ct + 3) * 1024 + e1);
                pnm[slot] = nvp[(ct + 3) * 16];
                psq[slot] = sqp[(ct + 3) * 16];
                pni[slot] = nip[(ct + 3) * 16];
            }

            f32x4 c0 = {0.f, 0.f, 0.f, 0.f};
            f32x4 c1 = {0.f, 0.f, 0.f, 0.f};
            c0 = __builtin_amdgcn_mfma_f32_16x16x32_f16(ah[0], bh0c, c0, 0, 0, 0);
            c1 = __builtin_amdgcn_mfma_f32_16x16x32_f16(ah[1], bh1c, c1, 0, 0, 0);
            c0 = __builtin_amdgcn_mfma_f32_16x16x32_f16(al[0], bh0c, c0, 0, 0, 0);
            c1 = __builtin_amdgcn_mfma_f32_16x16x32_f16(al[1], bh1c, c1, 0, 0, 0);
            f32x4 d = c0 + c1;

            float pr[4], s2[4], rc[4];
            #pragma unroll
            for (int ri = 0; ri < 4; ++ri) {
                pr[ri] = nri[ri] * nmi;
                s2[ri] = sq_r[ri] + sqmc;
                rc[ri] = __builtin_amdgcn_rcpf(nrE[ri] + nmc);
            }
            #pragma unroll
            for (int ri = 0; ri < 4; ++ri) {
                float dot = d[ri];
                float cs  = dot * pr[ri];
                float d2  = fmaxf(fmaf(dot, -2.f, s2[ri]), 0.f);
                float dn  = __builtin_amdgcn_sqrtf(d2);
                float a   = __expf(fmaf(dn, -rc[ri], cs));
                att_f[ct][ri] = a;
                rs[ri] += a;
            }
        }

        // rs: shfl over 16-lane group, exchange across this TEAM's 4 cg waves
        #pragma unroll
        for (int ri = 0; ri < 4; ++ri) {
            float v = rs[ri];
            v += __shfl_xor(v, 1);
            v += __shfl_xor(v, 2);
            v += __shfl_xor(v, 4);
            v += __shfl_xor(v, 8);
            rs[ri] = v;
        }
        if (l15 == 0) {
            #pragma unroll
            for (int ri = 0; ri < 4; ++ri)
                rs_s[((tm * 2 + pb) * 4 + cg) * 16 + g * 4 + ri] = rs[ri];
        }
        __syncthreads();
        #pragma unroll
        for (int ri = 0; ri < 4; ++ri) {
            const int rl = g * 4 + ri;
            const int base = (tm * 2 + pb) * 4;
            float tot = rs_s[(base + 0) * 16 + rl] + rs_s[(base + 1) * 16 + rl]
                      + rs_s[(base + 2) * 16 + rl] + rs_s[(base + 3) * 16 + rl];
            float rinv = __builtin_amdgcn_rcpf(tot + EPS);
            #pragma unroll
            for (int ct = 0; ct < 8; ++ct)
                acc[ct][ri] += att_f[ct][ri] * rinv;
        }
    }

    // combine teams via the os transpose buffer, then coalesced store
    __syncthreads();
    if (tm == 0) {
        #pragma unroll
        for (int ri = 0; ri < 4; ++ri)
            #pragma unroll
            for (int ct = 0; ct < 8; ++ct)
                os[(g * 4 + ri) * 516 + cg * 128 + ct * 16 + l15] = acc[ct][ri] * 0.125f;
    }
    __syncthreads();
    if (tm == 1) {
        #pragma unroll
        for (int ri = 0; ri < 4; ++ri)
            #pragma unroll
            for (int ct = 0; ct < 8; ++ct)
                os[(g * 4 + ri) * 516 + cg * 128 + ct * 16 + l15] += acc[ct][ri] * 0.125f;
    }
    __syncthreads();
    #pragma unroll
    for (int it = 0; it < 4; ++it) {
        const int idx4 = tid + it * 512;          // 2048 float4 = 16 x 512
        const int row  = idx4 >> 7;
        const int cc   = (idx4 & 127) * 4;
        float4 v = *(const float4*)&os[row * 516 + cc];
        *(float4*)(out + ((size_t)t * NN + n0 + row) * NN + cc) = v;
    }
}

extern "C" void kernel_launch(void* const* d_in, const int* in_sizes, int n_in,
                              void* d_out, int out_size, void* d_ws, size_t ws_size,
                              hipStream_t stream) {
    const float* x    = (const float*)d_in[0];
    const float* W    = (const float*)d_in[1];
    const float* bias = (const float*)d_in[2];
    float* out = (float*)d_out;

    const size_t ZELEMS = (size_t)BB * TT * NN * DD;
    const size_t NROWS  = (size_t)BB * TT * NN;
    _Float16* zh = (_Float16*)d_ws;
    _Float16* zl = zh + ZELEMS;
    float* sqv = (float*)(zh + 2 * ZELEMS);
    float* nvv = sqv + NROWS;
    float* nvi = nvv + NROWS;
    _Float16* whF = (_Float16*)(nvi + NROWS);   // 16KB
    _Float16* wlF = whF + 8192;                 // 16KB

    wsplit_kernel<<<dim3(1), dim3(256), 0, stream>>>(W, whF, wlF);
    z8_kernel<<<dim3(BB * (NN / 4)), dim3(256), 67584, stream>>>(x, whF, wlF, bias, zh, zl, sqv, nvv, nvi);
    att16_kernel<<<dim3(TT * (NN / 16)), dim3(512), LDSSZ_ATT, stream>>>(zh, zl, sqv, nvv, nvi, out);
}

// Round 21
// 102.129 us; speedup vs baseline: 1.2373x; 1.2373x over previous
//
#include <hip/hip_runtime.h>
#include <math.h>

#define BB 8
#define NN 512
#define FF 128
#define TT 32
#define DD 64
constexpr float EPS = 1e-6f;

typedef _Float16 half8 __attribute__((ext_vector_type(8)));
typedef float f32x4 __attribute__((ext_vector_type(4)));

extern __shared__ char dynsmem[];

__device__ __forceinline__ float fast_tanh(float v) {
    float e = __expf(2.f * v);
    return 1.f - 2.f * __builtin_amdgcn_rcpf(e + 1.f);
}

// ---------------- Stage 0: split W into MFMA-fragment-layout fp16 hi/lo tables ----------------
__global__ __launch_bounds__(256) void wsplit_kernel(const float* __restrict__ W,
                                                     _Float16* __restrict__ whF,
                                                     _Float16* __restrict__ wlF) {
    const int tid = threadIdx.x;
    #pragma unroll
    for (int k = 0; k < 4; ++k) {
        int u   = tid + k * 256;          // 0..1023
        int g   = u & 3;
        int l15 = (u >> 2) & 15;
        int sd  = u >> 6;                 // s*4+dt
        int s   = sd >> 2;
        int dt  = sd & 3;
        const float* src = W + (dt * 16 + l15) * 128 + s * 32 + g * 8;
        half8 hv, lv;
        #pragma unroll
        for (int i = 0; i < 8; ++i) {
            float f = src[i];
            hv[i] = (_Float16)f;
            lv[i] = (_Float16)(f - (float)hv[i]);
        }
        ((half8*)whF)[u] = hv;
        ((half8*)wlF)[u] = lv;
    }
}

// ---------------- Stage 1: z = tanh(x @ W^T + b) via split-fp16 MFMA, 2 n/block ----------------
// 4 waves = (n-slot ns = w>>1) x (d-half h = w&1). LDS = xs[2][4224] + sqpart[2][2][32]
// = 34304 B -> 4 blocks/CU (16 waves/CU; z8's 67.6KB allowed only 2 blocks -> latency-bound).
// grid: B * (N/2) = 2048 blocks, 256 threads
__global__ __launch_bounds__(256) void z10_kernel(const float* __restrict__ x,
                                                  const _Float16* __restrict__ whF,
                                                  const _Float16* __restrict__ wlF,
                                                  const float* __restrict__ bias,
                                                  _Float16* __restrict__ zh,
                                                  _Float16* __restrict__ zl,
                                                  float* __restrict__ sqv,
                                                  float* __restrict__ nvv,
                                                  float* __restrict__ nvi) {
    float* xs = (float*)dynsmem;              // 2 x 4224 floats
    float* sqpart = xs + 2 * 4224;            // [ns][h][32]
    const int tid = threadIdx.x;
    const int b  = blockIdx.x >> 8;
    const int n0 = (blockIdx.x & 255) * 2;

    // stage x[b][n0..n0+1][F][T] (8192 floats) -> xs[ns][t][f] (padded stride 132)
    const float4* x4 = (const float4*)(x + ((size_t)b * NN + n0) * FF * TT);
    #pragma unroll
    for (int it = 0; it < 8; ++it) {
        int idx4 = tid + it * 256;
        float4 v = x4[idx4];
        int e   = idx4 * 4;
        int ns2 = e >> 12;
        int rem = e & 4095;
        int f   = rem >> 5;
        int t   = rem & 31;
        float* base = xs + ns2 * 4224 + t * 132 + f;
        base[0 * 132] = v.x;
        base[1 * 132] = v.y;
        base[2 * 132] = v.z;
        base[3 * 132] = v.w;
    }
    __syncthreads();

    const int w    = tid >> 6;
    const int lane = tid & 63;
    const int l15  = lane & 15;
    const int g    = lane >> 4;
    const int ns   = w >> 1;        // n-slot
    const int h    = w & 1;         // d-half
    const int n    = n0 + ns;
    float* xs_w = xs + ns * 4224;

    // W-hi fragments for this wave's d-half: sd = s*4 + h*2 + dt'
    half8 wh[8];
    #pragma unroll
    for (int s = 0; s < 4; ++s)
        #pragma unroll
        for (int dt = 0; dt < 2; ++dt)
            wh[s * 2 + dt] = ((const half8*)whF)[(s * 4 + h * 2 + dt) * 64 + l15 * 4 + g];

    float bb[2];
    #pragma unroll
    for (int dt = 0; dt < 2; ++dt) bb[dt] = bias[(h * 2 + dt) * 16 + l15];

    f32x4 acc[2][2];
    #pragma unroll
    for (int dt = 0; dt < 2; ++dt)
        #pragma unroll
        for (int tt = 0; tt < 2; ++tt) acc[dt][tt] = f32x4{0.f, 0.f, 0.f, 0.f};

    #pragma unroll
    for (int s = 0; s < 4; ++s) {
        half8 ah[2], al[2];
        #pragma unroll
        for (int tt = 0; tt < 2; ++tt) {
            const float* ap = xs_w + (tt * 16 + l15) * 132 + s * 32 + g * 8;
            float4 p0 = *(const float4*)ap;
            float4 p1 = *(const float4*)(ap + 4);
            float fv[8] = {p0.x, p0.y, p0.z, p0.w, p1.x, p1.y, p1.z, p1.w};
            #pragma unroll
            for (int i = 0; i < 8; ++i) {
                ah[tt][i] = (_Float16)fv[i];
                al[tt][i] = (_Float16)(fv[i] - (float)ah[tt][i]);
            }
        }
        #pragma unroll
        for (int dt = 0; dt < 2; ++dt) {
            half8 wl_ = ((const half8*)wlF)[(s * 4 + h * 2 + dt) * 64 + l15 * 4 + g];
            acc[dt][0] = __builtin_amdgcn_mfma_f32_16x16x32_f16(ah[0], wh[s * 2 + dt], acc[dt][0], 0, 0, 0);
            acc[dt][1] = __builtin_amdgcn_mfma_f32_16x16x32_f16(ah[1], wh[s * 2 + dt], acc[dt][1], 0, 0, 0);
            acc[dt][0] = __builtin_amdgcn_mfma_f32_16x16x32_f16(al[0], wh[s * 2 + dt], acc[dt][0], 0, 0, 0);
            acc[dt][1] = __builtin_amdgcn_mfma_f32_16x16x32_f16(al[1], wh[s * 2 + dt], acc[dt][1], 0, 0, 0);
            acc[dt][0] = __builtin_amdgcn_mfma_f32_16x16x32_f16(ah[0], wl_, acc[dt][0], 0, 0, 0);
            acc[dt][1] = __builtin_amdgcn_mfma_f32_16x16x32_f16(ah[1], wl_, acc[dt][1], 0, 0, 0);
        }
    }
    __syncthreads();   // all A-frag reads of xs done before zsw overwrites it

    // bias + tanh -> zsw [t][68] (cols h*32..h*32+31); sq partial per row for this d-half
    float* zsw = xs_w;
    float sp[2][4];
    #pragma unroll
    for (int tt = 0; tt < 2; ++tt)
        #pragma unroll
        for (int ri = 0; ri < 4; ++ri) sp[tt][ri] = 0.f;
    #pragma unroll
    for (int dt = 0; dt < 2; ++dt)
        #pragma unroll
        for (int tt = 0; tt < 2; ++tt)
            #pragma unroll
            for (int ri = 0; ri < 4; ++ri) {
                float zf = fast_tanh(acc[dt][tt][ri] + bb[dt]);
                sp[tt][ri] += zf * zf;
                zsw[(tt * 16 + g * 4 + ri) * 68 + h * 32 + dt * 16 + l15] = zf;
            }
    // reduce sq over the 16 l15 lanes
    #pragma unroll
    for (int k = 1; k < 16; k <<= 1)
        #pragma unroll
        for (int tt = 0; tt < 2; ++tt)
            #pragma unroll
            for (int ri = 0; ri < 4; ++ri) sp[tt][ri] += __shfl_xor(sp[tt][ri], k);
    if (l15 == 0) {
        #pragma unroll
        for (int tt = 0; tt < 2; ++tt)
            #pragma unroll
            for (int ri = 0; ri < 4; ++ri)
                sqpart[(ns * 2 + h) * 32 + tt * 16 + g * 4 + ri] = sp[tt][ri];
    }
    __syncthreads();

    // readback: wave (ns,h) packs octets [h*4, h*4+4) of its n; lane -> (row, 2 octets)
    const int tr = lane >> 1;
    const int ob = h * 4 + (lane & 1) * 2;
    const size_t rowidx = ((size_t)b * TT + tr) * NN + n;
    _Float16* zhp = zh + rowidx * DD;
    _Float16* zlp = zl + rowidx * DD;
    #pragma unroll
    for (int j = 0; j < 2; ++j) {
        const int oct = ob + j;
        const float* qp = zsw + tr * 68 + oct * 8;
        float4 q0 = *(const float4*)qp;
        float4 q1 = *(const float4*)(qp + 4);
        float fv[8] = {q0.x, q0.y, q0.z, q0.w, q1.x, q1.y, q1.z, q1.w};
        half8 hv, lv;
        #pragma unroll
        for (int i = 0; i < 8; ++i) {
            hv[i] = (_Float16)fv[i];
            lv[i] = (_Float16)(fv[i] - (float)hv[i]);
        }
        const int so = (oct ^ (n & 7)) * 8;
        *(half8*)(zhp + so) = hv;
        *(half8*)(zlp + so) = lv;
    }
    if (h == 0 && !(lane & 1)) {
        float sqf = sqpart[(ns * 2 + 0) * 32 + tr] + sqpart[(ns * 2 + 1) * 32 + tr];
        float nv  = sqrtf(sqf) + EPS;
        sqv[rowidx] = sqf;
        nvv[rowidx] = nv;
        nvi[rowidx] = __builtin_amdgcn_rcpf(nv);
    }
}

// ---------------- Stage 2: L2-direct, depth-3 pipeline, rcp-precomputed (att15, unchanged) ----------------
#define RSOFS   33024
#define LDSSZ_ATT 34048

__global__ __launch_bounds__(512, 2) void att15_kernel(const _Float16* __restrict__ zh,
                                                       const _Float16* __restrict__ zl,
                                                       const float* __restrict__ sqv,
                                                       const float* __restrict__ nvv,
                                                       const float* __restrict__ nvi,
                                                       float* __restrict__ out) {
    char* lds = dynsmem;
    float* os   = (float*)lds;
    float* rs_s = (float*)(lds + RSOFS);   // [2][2][4][16]
    const int tid  = threadIdx.x;
    const int w    = tid >> 6;
    const int lane = tid & 63;
    const int l15  = lane & 15;
    const int g    = lane >> 4;
    const int rt   = w >> 2;
    const int cg   = w & 3;
    const int t    = blockIdx.x & 31;
    const int rg   = blockIdx.x >> 5;
    const int n0   = rg * 32;

    float acc[8][4];
    #pragma unroll
    for (int ct = 0; ct < 8; ++ct)
        #pragma unroll
        for (int ri = 0; ri < 4; ++ri) acc[ct][ri] = 0.f;

    float att_f[8][4];

    const int kq = l15 & 7;
    const int e0 = (g ^ kq) * 8;
    const int e1 = ((4 + g) ^ kq) * 8;
    const int arow = n0 + rt * 16 + l15;

    #pragma unroll 1
    for (int b = 0; b < BB; ++b) {
        const int pb = b & 1;
        const size_t nbase = ((size_t)b * TT + t) * NN;
        const size_t slab  = nbase * DD;

        half8 ah[2], al[2];
        {
            const size_t ro = slab + (size_t)arow * DD;
            ah[0] = *(const half8*)(zh + ro + e0);
            ah[1] = *(const half8*)(zh + ro + e1);
            al[0] = *(const half8*)(zl + ro + e0);
            al[1] = *(const half8*)(zl + ro + e1);
        }
        float nrE[4], sq_r[4], nri[4];
        #pragma unroll
        for (int ri = 0; ri < 4; ++ri) {
            const int rrow = n0 + rt * 16 + g * 4 + ri;
            nrE[ri]  = nvv[nbase + rrow] + EPS;
            sq_r[ri] = sqv[nbase + rrow];
            nri[ri]  = nvi[nbase + rrow];
        }

        float rs[4] = {0.f, 0.f, 0.f, 0.f};

        const _Float16* cb  = zh + slab + (size_t)(cg * 128 + l15) * DD;
        const float*    nvp = nvv + nbase + cg * 128 + l15;
        const float*    sqp = sqv + nbase + cg * 128 + l15;
        const float*    nip = nvi + nbase + cg * 128 + l15;
        half8 pb0[3], pb1[3];
        float pnm[3], psq[3], pni[3];
        #pragma unroll
        for (int p = 0; p < 3; ++p) {
            pb0[p] = *(const half8*)(cb + p * 1024 + e0);
            pb1[p] = *(const half8*)(cb + p * 1024 + e1);
            pnm[p] = nvp[p * 16];
            psq[p] = sqp[p * 16];
            pni[p] = nip[p * 16];
        }
        #pragma unroll
        for (int ct = 0; ct < 8; ++ct) {
            const int slot = ct % 3;
            half8 bh0c = pb0[slot], bh1c = pb1[slot];
            float nmc = pnm[slot], sqmc = psq[slot], nmi = pni[slot];
            if (ct + 3 < 8) {
                pb0[slot] = *(const half8*)(cb + (ct + 3) * 1024 + e0);
                pb1[slot] = *(const half8*)(cb + (ct + 3) * 1024 + e1);
                pnm[slot] = nvp[(ct + 3) * 16];
                psq[slot] = sqp[(ct + 3) * 16];
                pni[slot] = nip[(ct + 3) * 16];
            }

            f32x4 c0 = {0.f, 0.f, 0.f, 0.f};
            f32x4 c1 = {0.f, 0.f, 0.f, 0.f};
            c0 = __builtin_amdgcn_mfma_f32_16x16x32_f16(ah[0], bh0c, c0, 0, 0, 0);
            c1 = __builtin_amdgcn_mfma_f32_16x16x32_f16(ah[1], bh1c, c1, 0, 0, 0);
            c0 = __builtin_amdgcn_mfma_f32_16x16x32_f16(al[0], bh0c, c0, 0, 0, 0);
            c1 = __builtin_amdgcn_mfma_f32_16x16x32_f16(al[1], bh1c, c1, 0, 0, 0);
            f32x4 d = c0 + c1;

            float pr[4], s2[4], rc[4];
            #pragma unroll
            for (int ri = 0; ri < 4; ++ri) {
                pr[ri] = nri[ri] * nmi;
                s2[ri] = sq_r[ri] + sqmc;
                rc[ri] = __builtin_amdgcn_rcpf(nrE[ri] + nmc);
            }
            #pragma unroll
            for (int ri = 0; ri < 4; ++ri) {
                float dot = d[ri];
                float cs  = dot * pr[ri];
                float d2  = fmaxf(fmaf(dot, -2.f, s2[ri]), 0.f);
                float dn  = __builtin_amdgcn_sqrtf(d2);
                float a   = __expf(fmaf(dn, -rc[ri], cs));
                att_f[ct][ri] = a;
                rs[ri] += a;
            }
        }

        #pragma unroll
        for (int ri = 0; ri < 4; ++ri) {
            float v = rs[ri];
            v += __shfl_xor(v, 1);
            v += __shfl_xor(v, 2);
            v += __shfl_xor(v, 4);
            v += __shfl_xor(v, 8);
            rs[ri] = v;
        }
        if (l15 == 0) {
            #pragma unroll
            for (int ri = 0; ri < 4; ++ri)
                rs_s[((pb * 2 + rt) * 4 + cg) * 16 + g * 4 + ri] = rs[ri];
        }
        __syncthreads();
        #pragma unroll
        for (int ri = 0; ri < 4; ++ri) {
            const int rl = g * 4 + ri;
            const int base = (pb * 2 + rt) * 4;
            float tot = rs_s[(base + 0) * 16 + rl] + rs_s[(base + 1) * 16 + rl]
                      + rs_s[(base + 2) * 16 + rl] + rs_s[(base + 3) * 16 + rl];
            float rinv = __builtin_amdgcn_rcpf(tot + EPS);
            #pragma unroll
            for (int ct = 0; ct < 8; ++ct)
                acc[ct][ri] += att_f[ct][ri] * rinv;
        }
    }

    __syncthreads();
    for (int r = 0; r < 2; ++r) {
        if (rt == r) {
            #pragma unroll
            for (int ri = 0; ri < 4; ++ri)
                #pragma unroll
                for (int ct = 0; ct < 8; ++ct)
                    os[(g * 4 + ri) * 516 + cg * 128 + ct * 16 + l15] = acc[ct][ri] * 0.125f;
        }
        __syncthreads();
        #pragma unroll
        for (int it = 0; it < 4; ++it) {
            const int idx4 = tid + it * 512;
            const int row  = idx4 >> 7;
            const int cc   = (idx4 & 127) * 4;
            float4 v = *(const float4*)&os[row * 516 + cc];
            *(float4*)(out + ((size_t)t * NN + n0 + r * 16 + row) * NN + cc) = v;
        }
        __syncthreads();
    }
}

extern "C" void kernel_launch(void* const* d_in, const int* in_sizes, int n_in,
                              void* d_out, int out_size, void* d_ws, size_t ws_size,
                              hipStream_t stream) {
    const float* x    = (const float*)d_in[0];
    const float* W    = (const float*)d_in[1];
    const float* bias = (const float*)d_in[2];
    float* out = (float*)d_out;

    const size_t ZELEMS = (size_t)BB * TT * NN * DD;
    const size_t NROWS  = (size_t)BB * TT * NN;
    _Float16* zh = (_Float16*)d_ws;
    _Float16* zl = zh + ZELEMS;
    float* sqv = (float*)(zh + 2 * ZELEMS);
    float* nvv = sqv + NROWS;
    float* nvi = nvv + NROWS;
    _Float16* whF = (_Float16*)(nvi + NROWS);   // 16KB
    _Float16* wlF = whF + 8192;                 // 16KB

    wsplit_kernel<<<dim3(1), dim3(256), 0, stream>>>(W, whF, wlF);
    z10_kernel<<<dim3(BB * (NN / 2)), dim3(256), 34304, stream>>>(x, whF, wlF, bias, zh, zl, sqv, nvv, nvi);
    att15_kernel<<<dim3(TT * (NN / 32)), dim3(512), LDSSZ_ATT, stream>>>(zh, zl, sqv, nvv, nvi, out);
}